// Round 13
// baseline (339.349 us; speedup 1.0000x reference)
//
#include <hip/hip_runtime.h>

typedef __attribute__((ext_vector_type(8))) __bf16 bf16x8;
typedef __attribute__((ext_vector_type(4))) float f32x4;
typedef __attribute__((ext_vector_type(8))) unsigned short u16x8;

__device__ __forceinline__ float bf2f(unsigned short h) {
  union { unsigned int u; float f; } a; a.u = ((unsigned int)h) << 16; return a.f;
}
__device__ __forceinline__ unsigned short f2bf(float f) {
  union { float f; unsigned int u; } a; a.f = f;
  unsigned int u = a.u;
  u += 0x7fffu + ((u >> 16) & 1u);   // RNE
  return (unsigned short)(u >> 16);
}
// alias-safe 16B ops (memcpy → ds_read_b128 / global_load_dwordx4; no TBAA UB)
__device__ __forceinline__ bf16x8 ld_frag(const unsigned short* p) {
  bf16x8 r; __builtin_memcpy(&r, p, 16); return r;
}
__device__ __forceinline__ void cp16(unsigned short* dst, const unsigned short* src) {
  u16x8 t; __builtin_memcpy(&t, src, 16); __builtin_memcpy(dst, &t, 16);
}

// async global->LDS 16B DMA; dest = wave-uniform base + lane*16B in all uses.
#if __has_builtin(__builtin_amdgcn_global_load_lds)
typedef __attribute__((address_space(3))) unsigned int lds_u32;
typedef const __attribute__((address_space(1))) unsigned int glb_u32;
__device__ __forceinline__ void gload16(const unsigned short* g, unsigned short* l) {
  __builtin_amdgcn_global_load_lds((glb_u32*)g, (lds_u32*)l, 16, 0, 0);
}
#else
__device__ __forceinline__ void gload16(const unsigned short* g, unsigned short* l) {
  cp16(l, g);
}
#endif

// ---------------------------------------------------------------- fp32 -> bf16 bulk convert
__global__ __launch_bounds__(256) void cvt_kernel(
    const float* __restrict__ in, unsigned short* __restrict__ out, int n8)
{
  int i = blockIdx.x * 256 + threadIdx.x;
  if (i >= n8) return;
  float tf[8]; __builtin_memcpy(tf, &in[(size_t)i * 8], 32);
  unsigned short tu[8];
#pragma unroll
  for (int j = 0; j < 8; j++) tu[j] = f2bf(tf[j]);
  __builtin_memcpy(&out[(size_t)i * 8], tu, 16);
}

// ---------------------------------------------------------------- fused 4-weight transpose
__global__ __launch_bounds__(256) void transpose4_kernel(
    const float* __restrict__ w0, const float* __restrict__ w1,
    const float* __restrict__ w2, const float* __restrict__ w3,
    unsigned short* __restrict__ out)
{
  __shared__ unsigned short tile[64 * 65];
  const int z = blockIdx.z;
  const float* in = (z == 0) ? w0 : (z == 1) ? w1 : (z == 2) ? w2 : w3;
  unsigned short* o = out + (size_t)z * 1048576;
  const int dim = 1024;
  const int t = threadIdx.x;
  const int n0 = blockIdx.x * 64, k0 = blockIdx.y * 64;
#pragma unroll
  for (int e = 0; e < 16; e++) {
    int idx = e * 256 + t;
    int i = idx >> 6, j = idx & 63;
    tile[i * 65 + j] = f2bf(in[(size_t)(k0 + i) * dim + n0 + j]);
  }
  __syncthreads();
#pragma unroll
  for (int e = 0; e < 16; e++) {
    int idx = e * 256 + t;
    int i = idx >> 6, j = idx & 63;
    o[(size_t)(n0 + i) * dim + k0 + j] = tile[j * 65 + i];
  }
}

// ---------------------------------------------------------------- GEMM (B^T), 128x128 tile
__global__ __launch_bounds__(256) void gemm_bt_kernel(
    const unsigned short* __restrict__ A,
    const unsigned short* __restrict__ BT,
    const float* __restrict__ bias,
    unsigned short* __restrict__ C,
    int M, int N, int K, float cscale)
{
  __shared__ unsigned short As[128 * 32];
  __shared__ unsigned short Bs[128 * 32];
  const int tid  = threadIdx.x;
  const int wave = tid >> 6;
  const int lane = tid & 63;
  const int quad = lane >> 4;
  const int l16  = lane & 15;
  const int m0 = blockIdx.x * 128;
  const int n0 = blockIdx.y * 128;
  const int wm = (wave & 1) * 64;
  const int wn = (wave >> 1) * 64;

  const f32x4 fz = {0.0f, 0.0f, 0.0f, 0.0f};
  f32x4 acc[4][4];
#pragma unroll
  for (int i = 0; i < 4; i++)
#pragma unroll
    for (int j = 0; j < 4; j++) acc[i][j] = fz;

  const int srow0 = tid >> 2;
  const int scol  = (tid & 3) * 8;

  for (int k0 = 0; k0 < K; k0 += 32) {
#pragma unroll
    for (int i = 0; i < 2; i++) {
      int row = srow0 + i * 64;
      gload16(&A[(size_t)(m0 + row) * K + k0 + scol], &As[row * 32 + scol]);
      gload16(&BT[(size_t)(n0 + row) * K + k0 + scol], &Bs[row * 32 + scol]);
    }
    __syncthreads();
    bf16x8 afr[4], bfr[4];
#pragma unroll
    for (int mt = 0; mt < 4; mt++) afr[mt] = ld_frag(&As[(wm + mt * 16 + l16) * 32 + quad * 8]);
#pragma unroll
    for (int nt = 0; nt < 4; nt++) bfr[nt] = ld_frag(&Bs[(wn + nt * 16 + l16) * 32 + quad * 8]);
#pragma unroll
    for (int mt = 0; mt < 4; mt++)
#pragma unroll
      for (int nt = 0; nt < 4; nt++)
        acc[mt][nt] = __builtin_amdgcn_mfma_f32_16x16x32_bf16(afr[mt], bfr[nt], acc[mt][nt], 0, 0, 0);
    __syncthreads();
  }

#pragma unroll
  for (int nt = 0; nt < 4; nt++) {
    int col = n0 + wn + nt * 16 + l16;
    float bv = bias[col];
#pragma unroll
    for (int mt = 0; mt < 4; mt++) {
      int rowb = m0 + wm + mt * 16 + quad * 4;
#pragma unroll
      for (int r = 0; r < 4; r++)
        C[(size_t)(rowb + r) * N + col] = f2bf((acc[mt][nt][r] + bv) * cscale);
    }
  }
}

// ---------------------------------------------------------------- GEMM (B^T), 64x128 tile
// For small-M GEMMs (q-proj/out-proj, M=2048): grid (32,8)=256 blocks -> 1/CU
// (the 128-tile version gave only 128 blocks = half the GPU idle).
__global__ __launch_bounds__(256) void gemm_bt64_kernel(
    const unsigned short* __restrict__ A,
    const unsigned short* __restrict__ BT,
    const float* __restrict__ bias,
    unsigned short* __restrict__ C,
    int M, int N, int K, float cscale)
{
  __shared__ unsigned short As[64 * 32];
  __shared__ unsigned short Bs[128 * 32];
  const int tid  = threadIdx.x;
  const int wave = tid >> 6;
  const int lane = tid & 63;
  const int quad = lane >> 4;
  const int l16  = lane & 15;
  const int m0 = blockIdx.x * 64;
  const int n0 = blockIdx.y * 128;
  const int wm = (wave & 1) * 32;
  const int wn = (wave >> 1) * 64;

  const f32x4 fz = {0.0f, 0.0f, 0.0f, 0.0f};
  f32x4 acc[2][4];
#pragma unroll
  for (int i = 0; i < 2; i++)
#pragma unroll
    for (int j = 0; j < 4; j++) acc[i][j] = fz;

  const int srow0 = tid >> 2;        // 0..63
  const int scol  = (tid & 3) * 8;

  for (int k0 = 0; k0 < K; k0 += 32) {
    gload16(&A[(size_t)(m0 + srow0) * K + k0 + scol], &As[srow0 * 32 + scol]);
#pragma unroll
    for (int i = 0; i < 2; i++) {
      int row = srow0 + i * 64;
      gload16(&BT[(size_t)(n0 + row) * K + k0 + scol], &Bs[row * 32 + scol]);
    }
    __syncthreads();
    bf16x8 afr[2], bfr[4];
#pragma unroll
    for (int mt = 0; mt < 2; mt++) afr[mt] = ld_frag(&As[(wm + mt * 16 + l16) * 32 + quad * 8]);
#pragma unroll
    for (int nt = 0; nt < 4; nt++) bfr[nt] = ld_frag(&Bs[(wn + nt * 16 + l16) * 32 + quad * 8]);
#pragma unroll
    for (int mt = 0; mt < 2; mt++)
#pragma unroll
      for (int nt = 0; nt < 4; nt++)
        acc[mt][nt] = __builtin_amdgcn_mfma_f32_16x16x32_bf16(afr[mt], bfr[nt], acc[mt][nt], 0, 0, 0);
    __syncthreads();
  }

#pragma unroll
  for (int nt = 0; nt < 4; nt++) {
    int col = n0 + wn + nt * 16 + l16;
    float bv = bias[col];
#pragma unroll
    for (int mt = 0; mt < 2; mt++) {
      int rowb = m0 + wm + mt * 16 + quad * 4;
#pragma unroll
      for (int r = 0; r < 4; r++)
        C[(size_t)(rowb + r) * N + col] = f2bf((acc[mt][nt][r] + bv) * cscale);
    }
  }
}

// ---------------------------------------------------------------- V-proj GEMM, transposed output
// vt[((b*16+h)*64+dv) * 2048 + key] = (V @ Wv + bv)[b*2048+key][h*64+dv]
__global__ __launch_bounds__(256) void gemm_vt_kernel(
    const unsigned short* __restrict__ A,
    const unsigned short* __restrict__ BT,
    const float* __restrict__ bias,
    unsigned short* __restrict__ vt)
{
  __shared__ unsigned short As[128 * 32];
  __shared__ unsigned short Bs[128 * 32];
  __shared__ unsigned short Ts[4][64 * 72];
  const int K = 1024;
  const int tid  = threadIdx.x;
  const int wave = tid >> 6;
  const int lane = tid & 63;
  const int quad = lane >> 4;
  const int l16  = lane & 15;
  const int m0 = blockIdx.x * 128;
  const int n0 = blockIdx.y * 128;
  const int wm = (wave & 1) * 64;
  const int wn = (wave >> 1) * 64;

  const f32x4 fz = {0.0f, 0.0f, 0.0f, 0.0f};
  f32x4 acc[4][4];
#pragma unroll
  for (int i = 0; i < 4; i++)
#pragma unroll
    for (int j = 0; j < 4; j++) acc[i][j] = fz;

  const int srow0 = tid >> 2;
  const int scol  = (tid & 3) * 8;

  for (int k0 = 0; k0 < K; k0 += 32) {
#pragma unroll
    for (int i = 0; i < 2; i++) {
      int row = srow0 + i * 64;
      gload16(&A[(size_t)(m0 + row) * K + k0 + scol], &As[row * 32 + scol]);
      gload16(&BT[(size_t)(n0 + row) * K + k0 + scol], &Bs[row * 32 + scol]);
    }
    __syncthreads();
    bf16x8 afr[4], bfr[4];
#pragma unroll
    for (int mt = 0; mt < 4; mt++) afr[mt] = ld_frag(&As[(wm + mt * 16 + l16) * 32 + quad * 8]);
#pragma unroll
    for (int nt = 0; nt < 4; nt++) bfr[nt] = ld_frag(&Bs[(wn + nt * 16 + l16) * 32 + quad * 8]);
#pragma unroll
    for (int mt = 0; mt < 4; mt++)
#pragma unroll
      for (int nt = 0; nt < 4; nt++)
        acc[mt][nt] = __builtin_amdgcn_mfma_f32_16x16x32_bf16(afr[mt], bfr[nt], acc[mt][nt], 0, 0, 0);
    __syncthreads();
  }

#pragma unroll
  for (int nt = 0; nt < 4; nt++) {
    float bv = bias[n0 + wn + nt * 16 + l16];
#pragma unroll
    for (int mt = 0; mt < 4; mt++)
#pragma unroll
      for (int r = 0; r < 4; r++)
        Ts[wave][(nt * 16 + l16) * 72 + mt * 16 + quad * 4 + r] = f2bf(acc[mt][nt][r] + bv);
  }
  {
    const int R0 = m0 + wm;
    const int b  = R0 >> 11;
    const int key0 = R0 & 2047;
    const int col = n0 + wn + lane;
    const int h  = col >> 6, dv = col & 63;
    const size_t vtrow = ((size_t)(b * 16 + h)) * 64 + dv;
#pragma unroll
    for (int jb = 0; jb < 8; jb++)
      cp16((unsigned short*)&vt[vtrow * 2048 + key0 + jb * 8],
           &Ts[wave][lane * 72 + jb * 8]);
  }
}

// ---------------------------------------------------------------- attention helpers (verified R10-R12 logic)
__device__ __forceinline__ void attn_load_tile(
    const unsigned short* __restrict__ kp, const unsigned short* __restrict__ vt,
    const int* __restrict__ mask, size_t kbase, size_t vbase, int mbase,
    int kt, int quad, int l16,
    bf16x8 (&bk)[4][2], bf16x8 (&bv)[4][2], int (&mk)[4])
{
#pragma unroll
  for (int nt = 0; nt < 4; nt++) {
    const size_t krow = kbase + ((size_t)(kt * 64 + nt * 16 + l16)) * 1024;
#pragma unroll
    for (int kc = 0; kc < 2; kc++)
      bk[nt][kc] = ld_frag(&kp[krow + kc * 32 + quad * 8]);
    mk[nt] = mask[mbase + kt * 64 + nt * 16 + l16];
  }
#pragma unroll
  for (int dvt = 0; dvt < 4; dvt++) {
    const size_t vrow = vbase + ((size_t)(dvt * 16 + l16)) * 2048 + kt * 64;
#pragma unroll
    for (int kc = 0; kc < 2; kc++)
      bv[dvt][kc] = ld_frag(&vt[vrow + kc * 32 + quad * 8]);
  }
}

__device__ __forceinline__ void attn_compute_tile(
    const bf16x8 (&aq)[2], const bf16x8 (&bk)[4][2], const bf16x8 (&bv)[4][2],
    const int (&mk)[4], unsigned short* Ps, int quad, int l16,
    float (&m_i)[4], float (&l_i)[4], f32x4 (&O)[4])
{
  const f32x4 fz = {0.0f, 0.0f, 0.0f, 0.0f};
  // S = Q K^T (16 x 64); Q pre-scaled by 0.125 in q-proj
  f32x4 s[4];
#pragma unroll
  for (int nt = 0; nt < 4; nt++) s[nt] = fz;
#pragma unroll
  for (int nt = 0; nt < 4; nt++)
#pragma unroll
    for (int kc = 0; kc < 2; kc++)
      s[nt] = __builtin_amdgcn_mfma_f32_16x16x32_bf16(aq[kc], bk[nt][kc], s[nt], 0, 0, 0);

#pragma unroll
  for (int nt = 0; nt < 4; nt++) {
    bool ok = (mk[nt] != 0);
#pragma unroll
    for (int r = 0; r < 4; r++)
      s[nt][r] = ok ? s[nt][r] : -1e30f;
  }

  float mnew[4];
#pragma unroll
  for (int r = 0; r < 4; r++)
    mnew[r] = fmaxf(fmaxf(s[0][r], s[1][r]), fmaxf(s[2][r], s[3][r]));
#pragma unroll
  for (int off = 1; off < 16; off <<= 1)
#pragma unroll
    for (int r = 0; r < 4; r++) mnew[r] = fmaxf(mnew[r], __shfl_xor(mnew[r], off));
#pragma unroll
  for (int r = 0; r < 4; r++) mnew[r] = fmaxf(mnew[r], m_i[r]);

  float alpha[4], rs[4];
#pragma unroll
  for (int r = 0; r < 4; r++) {
    alpha[r] = __expf(m_i[r] - mnew[r]);
    m_i[r] = mnew[r];
    rs[r] = 0.0f;
  }
  // masked s = -1e30 -> exp underflows to exact 0
#pragma unroll
  for (int nt = 0; nt < 4; nt++)
#pragma unroll
    for (int r = 0; r < 4; r++) {
      float p = __expf(s[nt][r] - mnew[r]);
      rs[r] += p;
      Ps[(quad * 4 + r) * 72 + nt * 16 + l16] = f2bf(p);
    }
#pragma unroll
  for (int off = 1; off < 16; off <<= 1)
#pragma unroll
    for (int r = 0; r < 4; r++) rs[r] += __shfl_xor(rs[r], off);
#pragma unroll
  for (int r = 0; r < 4; r++) l_i[r] = l_i[r] * alpha[r] + rs[r];
#pragma unroll
  for (int d = 0; d < 4; d++)
#pragma unroll
    for (int r = 0; r < 4; r++) O[d][r] = O[d][r] * alpha[r];

  bf16x8 ap[2];
#pragma unroll
  for (int kc = 0; kc < 2; kc++)
    ap[kc] = ld_frag(&Ps[l16 * 72 + kc * 32 + quad * 8]);
#pragma unroll
  for (int dvt = 0; dvt < 4; dvt++)
#pragma unroll
    for (int kc = 0; kc < 2; kc++)
      O[dvt] = __builtin_amdgcn_mfma_f32_16x16x32_bf16(ap[kc], bv[dvt][kc], O[dvt], 0, 0, 0);
}

// ---------------------------------------------------------------- attention
// 256-thread block per (bh, 64-q-row group); grid 512 (2 blocks/CU),
// XCD-pinned (bh = bid&63). FOUR q-sets per loaded K/V tile: 4x arithmetic
// intensity per load (R12 proved 2x halved attn time; load/address VALU is
// the remaining scalable cost — softmax VALU is invariant). Interleaved
// 64-key tiles across waves; per-set exp-weighted combine through one
// reused LDS buffer.
__global__ __launch_bounds__(256) void attn_kernel(
    const unsigned short* __restrict__ qp,   // [B*512, 1024] bf16, pre-scaled x0.125
    const unsigned short* __restrict__ kp,   // [B*2048, 1024] bf16
    const unsigned short* __restrict__ vt,   // [B*16*64, 2048] bf16 (dv-major)
    const int* __restrict__ mask,            // [B, 2048]
    unsigned short* __restrict__ attn)       // [B*512, 1024] bf16
{
  __shared__ unsigned short Ps[4][16 * 72];
  __shared__ unsigned short Opart[4][16 * 64];    // reused across sets
  __shared__ float Mpart[4][16], Lpart[4][16];

  const int tid  = threadIdx.x;
  const int wave = tid >> 6;
  const int lane = tid & 63;
  const int quad = lane >> 4;
  const int l16  = lane & 15;
  const int bid  = blockIdx.x;
  const int bh = bid & 63;       // XCD = bid%8 = bh%8
  const int qg = bid >> 6;       // q-group 0..7 (64 rows each)
  const int b = bh >> 4, h = bh & 15;

  bf16x8 aq[4][2];
#pragma unroll
  for (int s = 0; s < 4; s++) {
    const size_t qbase = ((size_t)(b * 512 + qg * 64 + s * 16 + l16)) * 1024 + h * 64;
#pragma unroll
    for (int kc = 0; kc < 2; kc++)
      aq[s][kc] = ld_frag(&qp[qbase + kc * 32 + quad * 8]);
  }

  const f32x4 fz = {0.0f, 0.0f, 0.0f, 0.0f};
  float m_i[4][4], l_i[4][4];
  f32x4 O[4][4];
#pragma unroll
  for (int s = 0; s < 4; s++)
#pragma unroll
    for (int r = 0; r < 4; r++) { m_i[s][r] = -1e30f; l_i[s][r] = 0.0f; O[s][r] = fz; }

  const size_t kbase = ((size_t)(b * 2048)) * 1024 + h * 64;
  const size_t vbase = ((size_t)(bh * 64)) * 2048;
  const int mbase = b * 2048;

  for (int it = 0; it < 8; it++) {
    const int kt = it * 4 + wave;            // interleaved tiles
    bf16x8 bk[4][2], bv[4][2]; int mk[4];
    attn_load_tile(kp, vt, mask, kbase, vbase, mbase, kt, quad, l16, bk, bv, mk);
#pragma unroll
    for (int s = 0; s < 4; s++)
      attn_compute_tile(aq[s], bk, bv, mk, Ps[wave], quad, l16, m_i[s], l_i[s], O[s]);
  }

  // per-set combine through one reused LDS buffer
  for (int s = 0; s < 4; s++) {
#pragma unroll
    for (int dvt = 0; dvt < 4; dvt++)
#pragma unroll
      for (int r = 0; r < 4; r++)
        Opart[wave][(quad * 4 + r) * 64 + dvt * 16 + l16] = f2bf(O[s][dvt][r]);
    if (l16 == 0) {
#pragma unroll
      for (int r = 0; r < 4; r++) {
        Mpart[wave][quad * 4 + r] = m_i[s][r];
        Lpart[wave][quad * 4 + r] = l_i[s][r];
      }
    }
    __syncthreads();
#pragma unroll
    for (int r = 0; r < 4; r++) {
      const int row = quad * 4 + r;
      float mw[4], msx = -1e30f;
#pragma unroll
      for (int w = 0; w < 4; w++) { mw[w] = Mpart[w][row]; msx = fmaxf(msx, mw[w]); }
      float lsum = 0.0f, wt[4];
#pragma unroll
      for (int w = 0; w < 4; w++) { wt[w] = __expf(mw[w] - msx); lsum += wt[w] * Lpart[w][row]; }
      float inv = (lsum > 0.0f) ? (1.0f / lsum) : 0.0f;
      float of = 0.0f;
#pragma unroll
      for (int w = 0; w < 4; w++)
        of += wt[w] * bf2f(Opart[w][row * 64 + wave * 16 + l16]);
      const int grow = b * 512 + qg * 64 + s * 16 + row;
      attn[(size_t)grow * 1024 + h * 64 + wave * 16 + l16] = f2bf(of * inv);
    }
    __syncthreads();   // readers done before next set overwrites Opart
  }
}

// ---------------------------------------------------------------- layernorm
__global__ __launch_bounds__(256) void ln_kernel(
    const unsigned short* __restrict__ x,
    const float* __restrict__ resid,
    const float* __restrict__ gamma,
    const float* __restrict__ beta,
    float* __restrict__ out)
{
  const int row = blockIdx.x;
  const int t = threadIdx.x;
  const int wave = t >> 6, lane = t & 63;
  __shared__ float red[8];
  float v[4];
  float s1 = 0.0f, s2 = 0.0f;
#pragma unroll
  for (int i = 0; i < 4; i++) {
    int e = t + i * 256;
    float val = bf2f(x[(size_t)row * 1024 + e]) + resid[(size_t)row * 1024 + e];
    v[i] = val; s1 += val; s2 += val * val;
  }
#pragma unroll
  for (int off = 1; off < 64; off <<= 1) { s1 += __shfl_xor(s1, off); s2 += __shfl_xor(s2, off); }
  if (lane == 0) { red[wave] = s1; red[4 + wave] = s2; }
  __syncthreads();
  s1 = red[0] + red[1] + red[2] + red[3];
  s2 = red[4] + red[5] + red[6] + red[7];
  float mu  = s1 * (1.0f / 1024.0f);
  float var = s2 * (1.0f / 1024.0f) - mu * mu;
  float rstd = rsqrtf(var + 1e-5f);
#pragma unroll
  for (int i = 0; i < 4; i++) {
    int e = t + i * 256;
    out[(size_t)row * 1024 + e] = (v[i] - mu) * rstd * gamma[e] + beta[e];
  }
}

// ---------------------------------------------------------------- launch
extern "C" void kernel_launch(void* const* d_in, const int* in_sizes, int n_in,
                              void* d_out, int out_size, void* d_ws, size_t ws_size,
                              hipStream_t stream) {
  (void)out_size; (void)ws_size;
  const float* Q = (const float*)d_in[0];
  const float* K = (const float*)d_in[1];
  const float* V = (const float*)d_in[2];

  int ix = 3;
  if (ix < n_in && in_sizes[ix] == 1) ix++;   // skip node_num scalar if passed
  const int* mask  = (const int*)d_in[ix++];
  const float* Wq = (const float*)d_in[ix++]; const float* bq = (const float*)d_in[ix++];
  const float* Wk = (const float*)d_in[ix++]; const float* bk = (const float*)d_in[ix++];
  const float* Wv = (const float*)d_in[ix++]; const float* bv = (const float*)d_in[ix++];
  const float* Wo = (const float*)d_in[ix++]; const float* bo = (const float*)d_in[ix++];
  const float* gm = (const float*)d_in[ix++]; const float* bt = (const float*)d_in[ix++];

  char* ws = (char*)d_ws;
  dim3 blk(256);

  // ws layout (64 MB): WT4 8 | qp 4 | kp 16 | vt 16 | at 4 (alias qb) | kvb 16
  unsigned short* WT4 = (unsigned short*)(ws);
  unsigned short* qp  = (unsigned short*)(ws + (8ull  << 20));
  unsigned short* kp  = (unsigned short*)(ws + (12ull << 20));
  unsigned short* vt  = (unsigned short*)(ws + (28ull << 20));
  unsigned short* at  = (unsigned short*)(ws + (44ull << 20));
  unsigned short* qb  = at;                       // dead before attn
  unsigned short* kvb = (unsigned short*)(ws + (48ull << 20));

  cvt_kernel<<<dim3(1024), blk, 0, stream>>>(Q, qb, 262144);
  cvt_kernel<<<dim3(4096), blk, 0, stream>>>(K, kvb, 1048576);
  transpose4_kernel<<<dim3(16, 16, 4), blk, 0, stream>>>(Wq, Wk, Wv, Wo, WT4);

  gemm_bt64_kernel<<<dim3(32, 8), blk, 0, stream>>>(qb, WT4, bq, qp, 2048, 1024, 1024, 0.125f);
  gemm_bt_kernel<<<dim3(64, 8), blk, 0, stream>>>(kvb, WT4 + 1048576, bk, kp, 8192, 1024, 1024, 1.0f);
  cvt_kernel<<<dim3(4096), blk, 0, stream>>>(V, kvb, 1048576);
  gemm_vt_kernel<<<dim3(64, 8), blk, 0, stream>>>(kvb, WT4 + 2097152, bv, vt);

  attn_kernel<<<dim3(512), blk, 0, stream>>>(qp, kp, vt, mask, at);

  gemm_bt64_kernel<<<dim3(32, 8), blk, 0, stream>>>(at, WT4 + 3145728, bo, qp, 2048, 1024, 1024, 1.0f);
  ln_kernel<<<dim3(2048), blk, 0, stream>>>(qp, Q, gm, bt, (float*)d_out);
}

// Round 14
// 320.108 us; speedup vs baseline: 1.0601x; 1.0601x over previous
//
#include <hip/hip_runtime.h>

typedef __attribute__((ext_vector_type(8))) __bf16 bf16x8;
typedef __attribute__((ext_vector_type(4))) float f32x4;
typedef __attribute__((ext_vector_type(8))) unsigned short u16x8;

__device__ __forceinline__ float bf2f(unsigned short h) {
  union { unsigned int u; float f; } a; a.u = ((unsigned int)h) << 16; return a.f;
}
__device__ __forceinline__ unsigned short f2bf(float f) {
  union { float f; unsigned int u; } a; a.f = f;
  unsigned int u = a.u;
  u += 0x7fffu + ((u >> 16) & 1u);   // RNE
  return (unsigned short)(u >> 16);
}
// alias-safe 16B ops (memcpy → ds_read_b128 / global_load_dwordx4; no TBAA UB)
__device__ __forceinline__ bf16x8 ld_frag(const unsigned short* p) {
  bf16x8 r; __builtin_memcpy(&r, p, 16); return r;
}
__device__ __forceinline__ void cp16(unsigned short* dst, const unsigned short* src) {
  u16x8 t; __builtin_memcpy(&t, src, 16); __builtin_memcpy(dst, &t, 16);
}

// async global->LDS 16B DMA; dest = wave-uniform base + lane*16B in all uses.
#if __has_builtin(__builtin_amdgcn_global_load_lds)
typedef __attribute__((address_space(3))) unsigned int lds_u32;
typedef const __attribute__((address_space(1))) unsigned int glb_u32;
__device__ __forceinline__ void gload16(const unsigned short* g, unsigned short* l) {
  __builtin_amdgcn_global_load_lds((glb_u32*)g, (lds_u32*)l, 16, 0, 0);
}
#else
__device__ __forceinline__ void gload16(const unsigned short* g, unsigned short* l) {
  cp16(l, g);
}
#endif

// ---------------------------------------------------------------- fp32 -> bf16 bulk convert
__global__ __launch_bounds__(256) void cvt_kernel(
    const float* __restrict__ in, unsigned short* __restrict__ out, int n8)
{
  int i = blockIdx.x * 256 + threadIdx.x;
  if (i >= n8) return;
  float tf[8]; __builtin_memcpy(tf, &in[(size_t)i * 8], 32);
  unsigned short tu[8];
#pragma unroll
  for (int j = 0; j < 8; j++) tu[j] = f2bf(tf[j]);
  __builtin_memcpy(&out[(size_t)i * 8], tu, 16);
}

// ---------------------------------------------------------------- fused 4-weight transpose
__global__ __launch_bounds__(256) void transpose4_kernel(
    const float* __restrict__ w0, const float* __restrict__ w1,
    const float* __restrict__ w2, const float* __restrict__ w3,
    unsigned short* __restrict__ out)
{
  __shared__ unsigned short tile[64 * 65];
  const int z = blockIdx.z;
  const float* in = (z == 0) ? w0 : (z == 1) ? w1 : (z == 2) ? w2 : w3;
  unsigned short* o = out + (size_t)z * 1048576;
  const int dim = 1024;
  const int t = threadIdx.x;
  const int n0 = blockIdx.x * 64, k0 = blockIdx.y * 64;
#pragma unroll
  for (int e = 0; e < 16; e++) {
    int idx = e * 256 + t;
    int i = idx >> 6, j = idx & 63;
    tile[i * 65 + j] = f2bf(in[(size_t)(k0 + i) * dim + n0 + j]);
  }
  __syncthreads();
#pragma unroll
  for (int e = 0; e < 16; e++) {
    int idx = e * 256 + t;
    int i = idx >> 6, j = idx & 63;
    o[(size_t)(n0 + i) * dim + k0 + j] = tile[j * 65 + i];
  }
}

// ---------------------------------------------------------------- GEMM (B^T), 128x128 tile
__global__ __launch_bounds__(256) void gemm_bt_kernel(
    const unsigned short* __restrict__ A,
    const unsigned short* __restrict__ BT,
    const float* __restrict__ bias,
    unsigned short* __restrict__ C,
    int M, int N, int K, float cscale)
{
  __shared__ unsigned short As[128 * 32];
  __shared__ unsigned short Bs[128 * 32];
  const int tid  = threadIdx.x;
  const int wave = tid >> 6;
  const int lane = tid & 63;
  const int quad = lane >> 4;
  const int l16  = lane & 15;
  const int m0 = blockIdx.x * 128;
  const int n0 = blockIdx.y * 128;
  const int wm = (wave & 1) * 64;
  const int wn = (wave >> 1) * 64;

  const f32x4 fz = {0.0f, 0.0f, 0.0f, 0.0f};
  f32x4 acc[4][4];
#pragma unroll
  for (int i = 0; i < 4; i++)
#pragma unroll
    for (int j = 0; j < 4; j++) acc[i][j] = fz;

  const int srow0 = tid >> 2;
  const int scol  = (tid & 3) * 8;

  for (int k0 = 0; k0 < K; k0 += 32) {
#pragma unroll
    for (int i = 0; i < 2; i++) {
      int row = srow0 + i * 64;
      gload16(&A[(size_t)(m0 + row) * K + k0 + scol], &As[row * 32 + scol]);
      gload16(&BT[(size_t)(n0 + row) * K + k0 + scol], &Bs[row * 32 + scol]);
    }
    __syncthreads();
    bf16x8 afr[4], bfr[4];
#pragma unroll
    for (int mt = 0; mt < 4; mt++) afr[mt] = ld_frag(&As[(wm + mt * 16 + l16) * 32 + quad * 8]);
#pragma unroll
    for (int nt = 0; nt < 4; nt++) bfr[nt] = ld_frag(&Bs[(wn + nt * 16 + l16) * 32 + quad * 8]);
#pragma unroll
    for (int mt = 0; mt < 4; mt++)
#pragma unroll
      for (int nt = 0; nt < 4; nt++)
        acc[mt][nt] = __builtin_amdgcn_mfma_f32_16x16x32_bf16(afr[mt], bfr[nt], acc[mt][nt], 0, 0, 0);
    __syncthreads();
  }

#pragma unroll
  for (int nt = 0; nt < 4; nt++) {
    int col = n0 + wn + nt * 16 + l16;
    float bv = bias[col];
#pragma unroll
    for (int mt = 0; mt < 4; mt++) {
      int rowb = m0 + wm + mt * 16 + quad * 4;
#pragma unroll
      for (int r = 0; r < 4; r++)
        C[(size_t)(rowb + r) * N + col] = f2bf((acc[mt][nt][r] + bv) * cscale);
    }
  }
}

// ---------------------------------------------------------------- GEMM (B^T), 64x128 tile
// For small-M GEMMs (q-proj/out-proj, M=2048): grid (32,8)=256 blocks -> 1/CU.
__global__ __launch_bounds__(256) void gemm_bt64_kernel(
    const unsigned short* __restrict__ A,
    const unsigned short* __restrict__ BT,
    const float* __restrict__ bias,
    unsigned short* __restrict__ C,
    int M, int N, int K, float cscale)
{
  __shared__ unsigned short As[64 * 32];
  __shared__ unsigned short Bs[128 * 32];
  const int tid  = threadIdx.x;
  const int wave = tid >> 6;
  const int lane = tid & 63;
  const int quad = lane >> 4;
  const int l16  = lane & 15;
  const int m0 = blockIdx.x * 64;
  const int n0 = blockIdx.y * 128;
  const int wm = (wave & 1) * 32;
  const int wn = (wave >> 1) * 64;

  const f32x4 fz = {0.0f, 0.0f, 0.0f, 0.0f};
  f32x4 acc[2][4];
#pragma unroll
  for (int i = 0; i < 2; i++)
#pragma unroll
    for (int j = 0; j < 4; j++) acc[i][j] = fz;

  const int srow0 = tid >> 2;        // 0..63
  const int scol  = (tid & 3) * 8;

  for (int k0 = 0; k0 < K; k0 += 32) {
    gload16(&A[(size_t)(m0 + srow0) * K + k0 + scol], &As[srow0 * 32 + scol]);
#pragma unroll
    for (int i = 0; i < 2; i++) {
      int row = srow0 + i * 64;
      gload16(&BT[(size_t)(n0 + row) * K + k0 + scol], &Bs[row * 32 + scol]);
    }
    __syncthreads();
    bf16x8 afr[2], bfr[4];
#pragma unroll
    for (int mt = 0; mt < 2; mt++) afr[mt] = ld_frag(&As[(wm + mt * 16 + l16) * 32 + quad * 8]);
#pragma unroll
    for (int nt = 0; nt < 4; nt++) bfr[nt] = ld_frag(&Bs[(wn + nt * 16 + l16) * 32 + quad * 8]);
#pragma unroll
    for (int mt = 0; mt < 2; mt++)
#pragma unroll
      for (int nt = 0; nt < 4; nt++)
        acc[mt][nt] = __builtin_amdgcn_mfma_f32_16x16x32_bf16(afr[mt], bfr[nt], acc[mt][nt], 0, 0, 0);
    __syncthreads();
  }

#pragma unroll
  for (int nt = 0; nt < 4; nt++) {
    int col = n0 + wn + nt * 16 + l16;
    float bv = bias[col];
#pragma unroll
    for (int mt = 0; mt < 2; mt++) {
      int rowb = m0 + wm + mt * 16 + quad * 4;
#pragma unroll
      for (int r = 0; r < 4; r++)
        C[(size_t)(rowb + r) * N + col] = f2bf((acc[mt][nt][r] + bv) * cscale);
    }
  }
}

// ---------------------------------------------------------------- V-proj GEMM, transposed output
// vt[((b*16+h)*64+dv) * 2048 + key] = (V @ Wv + bv)[b*2048+key][h*64+dv]
__global__ __launch_bounds__(256) void gemm_vt_kernel(
    const unsigned short* __restrict__ A,
    const unsigned short* __restrict__ BT,
    const float* __restrict__ bias,
    unsigned short* __restrict__ vt)
{
  __shared__ unsigned short As[128 * 32];
  __shared__ unsigned short Bs[128 * 32];
  __shared__ unsigned short Ts[4][64 * 72];
  const int K = 1024;
  const int tid  = threadIdx.x;
  const int wave = tid >> 6;
  const int lane = tid & 63;
  const int quad = lane >> 4;
  const int l16  = lane & 15;
  const int m0 = blockIdx.x * 128;
  const int n0 = blockIdx.y * 128;
  const int wm = (wave & 1) * 64;
  const int wn = (wave >> 1) * 64;

  const f32x4 fz = {0.0f, 0.0f, 0.0f, 0.0f};
  f32x4 acc[4][4];
#pragma unroll
  for (int i = 0; i < 4; i++)
#pragma unroll
    for (int j = 0; j < 4; j++) acc[i][j] = fz;

  const int srow0 = tid >> 2;
  const int scol  = (tid & 3) * 8;

  for (int k0 = 0; k0 < K; k0 += 32) {
#pragma unroll
    for (int i = 0; i < 2; i++) {
      int row = srow0 + i * 64;
      gload16(&A[(size_t)(m0 + row) * K + k0 + scol], &As[row * 32 + scol]);
      gload16(&BT[(size_t)(n0 + row) * K + k0 + scol], &Bs[row * 32 + scol]);
    }
    __syncthreads();
    bf16x8 afr[4], bfr[4];
#pragma unroll
    for (int mt = 0; mt < 4; mt++) afr[mt] = ld_frag(&As[(wm + mt * 16 + l16) * 32 + quad * 8]);
#pragma unroll
    for (int nt = 0; nt < 4; nt++) bfr[nt] = ld_frag(&Bs[(wn + nt * 16 + l16) * 32 + quad * 8]);
#pragma unroll
    for (int mt = 0; mt < 4; mt++)
#pragma unroll
      for (int nt = 0; nt < 4; nt++)
        acc[mt][nt] = __builtin_amdgcn_mfma_f32_16x16x32_bf16(afr[mt], bfr[nt], acc[mt][nt], 0, 0, 0);
    __syncthreads();
  }

#pragma unroll
  for (int nt = 0; nt < 4; nt++) {
    float bv = bias[n0 + wn + nt * 16 + l16];
#pragma unroll
    for (int mt = 0; mt < 4; mt++)
#pragma unroll
      for (int r = 0; r < 4; r++)
        Ts[wave][(nt * 16 + l16) * 72 + mt * 16 + quad * 4 + r] = f2bf(acc[mt][nt][r] + bv);
  }
  {
    const int R0 = m0 + wm;
    const int b  = R0 >> 11;
    const int key0 = R0 & 2047;
    const int col = n0 + wn + lane;
    const int h  = col >> 6, dv = col & 63;
    const size_t vtrow = ((size_t)(b * 16 + h)) * 64 + dv;
#pragma unroll
    for (int jb = 0; jb < 8; jb++)
      cp16((unsigned short*)&vt[vtrow * 2048 + key0 + jb * 8],
           &Ts[wave][lane * 72 + jb * 8]);
  }
}

// ---------------------------------------------------------------- attention helpers (verified R10-R12 logic)
__device__ __forceinline__ void attn_load_tile(
    const unsigned short* __restrict__ kp, const unsigned short* __restrict__ vt,
    const int* __restrict__ mask, size_t kbase, size_t vbase, int mbase,
    int kt, int quad, int l16,
    bf16x8 (&bk)[4][2], bf16x8 (&bv)[4][2], int (&mk)[4])
{
#pragma unroll
  for (int nt = 0; nt < 4; nt++) {
    const size_t krow = kbase + ((size_t)(kt * 64 + nt * 16 + l16)) * 1024;
#pragma unroll
    for (int kc = 0; kc < 2; kc++)
      bk[nt][kc] = ld_frag(&kp[krow + kc * 32 + quad * 8]);
    mk[nt] = mask[mbase + kt * 64 + nt * 16 + l16];
  }
#pragma unroll
  for (int dvt = 0; dvt < 4; dvt++) {
    const size_t vrow = vbase + ((size_t)(dvt * 16 + l16)) * 2048 + kt * 64;
#pragma unroll
    for (int kc = 0; kc < 2; kc++)
      bv[dvt][kc] = ld_frag(&vt[vrow + kc * 32 + quad * 8]);
  }
}

__device__ __forceinline__ void attn_compute_tile(
    const bf16x8 (&aq)[2], const bf16x8 (&bk)[4][2], const bf16x8 (&bv)[4][2],
    const int (&mk)[4], unsigned short* Ps, int quad, int l16,
    float (&m_i)[4], float (&l_i)[4], f32x4 (&O)[4])
{
  const f32x4 fz = {0.0f, 0.0f, 0.0f, 0.0f};
  // S = Q K^T (16 x 64); Q pre-scaled by 0.125 in q-proj
  f32x4 s[4];
#pragma unroll
  for (int nt = 0; nt < 4; nt++) s[nt] = fz;
#pragma unroll
  for (int nt = 0; nt < 4; nt++)
#pragma unroll
    for (int kc = 0; kc < 2; kc++)
      s[nt] = __builtin_amdgcn_mfma_f32_16x16x32_bf16(aq[kc], bk[nt][kc], s[nt], 0, 0, 0);

#pragma unroll
  for (int nt = 0; nt < 4; nt++) {
    bool ok = (mk[nt] != 0);
#pragma unroll
    for (int r = 0; r < 4; r++)
      s[nt][r] = ok ? s[nt][r] : -1e30f;
  }

  float mnew[4];
#pragma unroll
  for (int r = 0; r < 4; r++)
    mnew[r] = fmaxf(fmaxf(s[0][r], s[1][r]), fmaxf(s[2][r], s[3][r]));
#pragma unroll
  for (int off = 1; off < 16; off <<= 1)
#pragma unroll
    for (int r = 0; r < 4; r++) mnew[r] = fmaxf(mnew[r], __shfl_xor(mnew[r], off));
#pragma unroll
  for (int r = 0; r < 4; r++) mnew[r] = fmaxf(mnew[r], m_i[r]);

  float alpha[4], rs[4];
#pragma unroll
  for (int r = 0; r < 4; r++) {
    alpha[r] = __expf(m_i[r] - mnew[r]);
    m_i[r] = mnew[r];
    rs[r] = 0.0f;
  }
  // masked s = -1e30 -> exp underflows to exact 0
#pragma unroll
  for (int nt = 0; nt < 4; nt++)
#pragma unroll
    for (int r = 0; r < 4; r++) {
      float p = __expf(s[nt][r] - mnew[r]);
      rs[r] += p;
      Ps[(quad * 4 + r) * 72 + nt * 16 + l16] = f2bf(p);
    }
#pragma unroll
  for (int off = 1; off < 16; off <<= 1)
#pragma unroll
    for (int r = 0; r < 4; r++) rs[r] += __shfl_xor(rs[r], off);
#pragma unroll
  for (int r = 0; r < 4; r++) l_i[r] = l_i[r] * alpha[r] + rs[r];
#pragma unroll
  for (int d = 0; d < 4; d++)
#pragma unroll
    for (int r = 0; r < 4; r++) O[d][r] = O[d][r] * alpha[r];

  bf16x8 ap[2];
#pragma unroll
  for (int kc = 0; kc < 2; kc++)
    ap[kc] = ld_frag(&Ps[l16 * 72 + kc * 32 + quad * 8]);
#pragma unroll
  for (int dvt = 0; dvt < 4; dvt++)
#pragma unroll
    for (int kc = 0; kc < 2; kc++)
      O[dvt] = __builtin_amdgcn_mfma_f32_16x16x32_bf16(ap[kc], bv[dvt][kc], O[dvt], 0, 0, 0);
}

// ---------------------------------------------------------------- attention
// EXACT R12 configuration (best measured: 76.4 us) — 256-thread block per
// (bh, 32-q-row group); grid 1024, XCD-pinned (bh=bid&63). TWO q-sets per
// loaded K/V tile (R13's 4-set variant regressed: VGPR 192, occ 10.7%).
__global__ __launch_bounds__(256) void attn_kernel(
    const unsigned short* __restrict__ qp,   // [B*512, 1024] bf16, pre-scaled x0.125
    const unsigned short* __restrict__ kp,   // [B*2048, 1024] bf16
    const unsigned short* __restrict__ vt,   // [B*16*64, 2048] bf16 (dv-major)
    const int* __restrict__ mask,            // [B, 2048]
    unsigned short* __restrict__ attn)       // [B*512, 1024] bf16
{
  __shared__ unsigned short Ps[4][16 * 72];
  __shared__ unsigned short Opart[2][4][16 * 64];   // bf16 partials
  __shared__ float Mpart[2][4][16], Lpart[2][4][16];

  const int tid  = threadIdx.x;
  const int wave = tid >> 6;
  const int lane = tid & 63;
  const int quad = lane >> 4;
  const int l16  = lane & 15;
  const int bid  = blockIdx.x;
  const int bh = bid & 63;       // XCD = bid%8 = bh%8
  const int qg = bid >> 6;       // q-group 0..15 (32 rows each)
  const int b = bh >> 4, h = bh & 15;

  bf16x8 aq[2][2];
#pragma unroll
  for (int s = 0; s < 2; s++) {
    const size_t qbase = ((size_t)(b * 512 + qg * 32 + s * 16 + l16)) * 1024 + h * 64;
#pragma unroll
    for (int kc = 0; kc < 2; kc++)
      aq[s][kc] = ld_frag(&qp[qbase + kc * 32 + quad * 8]);
  }

  const f32x4 fz = {0.0f, 0.0f, 0.0f, 0.0f};
  float m_i[2][4], l_i[2][4];
  f32x4 O[2][4];
#pragma unroll
  for (int s = 0; s < 2; s++)
#pragma unroll
    for (int r = 0; r < 4; r++) { m_i[s][r] = -1e30f; l_i[s][r] = 0.0f; O[s][r] = fz; }

  const size_t kbase = ((size_t)(b * 2048)) * 1024 + h * 64;
  const size_t vbase = ((size_t)(bh * 64)) * 2048;
  const int mbase = b * 2048;

  for (int it = 0; it < 8; it++) {
    const int kt = it * 4 + wave;            // interleaved tiles
    bf16x8 bk[4][2], bv[4][2]; int mk[4];
    attn_load_tile(kp, vt, mask, kbase, vbase, mbase, kt, quad, l16, bk, bv, mk);
    attn_compute_tile(aq[0], bk, bv, mk, Ps[wave], quad, l16, m_i[0], l_i[0], O[0]);
    attn_compute_tile(aq[1], bk, bv, mk, Ps[wave], quad, l16, m_i[1], l_i[1], O[1]);
  }

  // post partials and combine (per q-set)
#pragma unroll
  for (int s = 0; s < 2; s++) {
#pragma unroll
    for (int dvt = 0; dvt < 4; dvt++)
#pragma unroll
      for (int r = 0; r < 4; r++)
        Opart[s][wave][(quad * 4 + r) * 64 + dvt * 16 + l16] = f2bf(O[s][dvt][r]);
    if (l16 == 0) {
#pragma unroll
      for (int r = 0; r < 4; r++) {
        Mpart[s][wave][quad * 4 + r] = m_i[s][r];
        Lpart[s][wave][quad * 4 + r] = l_i[s][r];
      }
    }
  }
  __syncthreads();

#pragma unroll
  for (int s = 0; s < 2; s++) {
#pragma unroll
    for (int r = 0; r < 4; r++) {
      const int row = quad * 4 + r;
      float mw[4], msx = -1e30f;
#pragma unroll
      for (int w = 0; w < 4; w++) { mw[w] = Mpart[s][w][row]; msx = fmaxf(msx, mw[w]); }
      float lsum = 0.0f, wt[4];
#pragma unroll
      for (int w = 0; w < 4; w++) { wt[w] = __expf(mw[w] - msx); lsum += wt[w] * Lpart[s][w][row]; }
      float inv = (lsum > 0.0f) ? (1.0f / lsum) : 0.0f;
      float of = 0.0f;
#pragma unroll
      for (int w = 0; w < 4; w++)
        of += wt[w] * bf2f(Opart[s][w][row * 64 + wave * 16 + l16]);
      const int grow = b * 512 + qg * 32 + s * 16 + row;
      attn[(size_t)grow * 1024 + h * 64 + wave * 16 + l16] = f2bf(of * inv);
    }
  }
}

// ---------------------------------------------------------------- layernorm
__global__ __launch_bounds__(256) void ln_kernel(
    const unsigned short* __restrict__ x,
    const float* __restrict__ resid,
    const float* __restrict__ gamma,
    const float* __restrict__ beta,
    float* __restrict__ out)
{
  const int row = blockIdx.x;
  const int t = threadIdx.x;
  const int wave = t >> 6, lane = t & 63;
  __shared__ float red[8];
  float v[4];
  float s1 = 0.0f, s2 = 0.0f;
#pragma unroll
  for (int i = 0; i < 4; i++) {
    int e = t + i * 256;
    float val = bf2f(x[(size_t)row * 1024 + e]) + resid[(size_t)row * 1024 + e];
    v[i] = val; s1 += val; s2 += val * val;
  }
#pragma unroll
  for (int off = 1; off < 64; off <<= 1) { s1 += __shfl_xor(s1, off); s2 += __shfl_xor(s2, off); }
  if (lane == 0) { red[wave] = s1; red[4 + wave] = s2; }
  __syncthreads();
  s1 = red[0] + red[1] + red[2] + red[3];
  s2 = red[4] + red[5] + red[6] + red[7];
  float mu  = s1 * (1.0f / 1024.0f);
  float var = s2 * (1.0f / 1024.0f) - mu * mu;
  float rstd = rsqrtf(var + 1e-5f);
#pragma unroll
  for (int i = 0; i < 4; i++) {
    int e = t + i * 256;
    out[(size_t)row * 1024 + e] = (v[i] - mu) * rstd * gamma[e] + beta[e];
  }
}

// ---------------------------------------------------------------- launch
extern "C" void kernel_launch(void* const* d_in, const int* in_sizes, int n_in,
                              void* d_out, int out_size, void* d_ws, size_t ws_size,
                              hipStream_t stream) {
  (void)out_size; (void)ws_size;
  const float* Q = (const float*)d_in[0];
  const float* K = (const float*)d_in[1];
  const float* V = (const float*)d_in[2];

  int ix = 3;
  if (ix < n_in && in_sizes[ix] == 1) ix++;   // skip node_num scalar if passed
  const int* mask  = (const int*)d_in[ix++];
  const float* Wq = (const float*)d_in[ix++]; const float* bq = (const float*)d_in[ix++];
  const float* Wk = (const float*)d_in[ix++]; const float* bk = (const float*)d_in[ix++];
  const float* Wv = (const float*)d_in[ix++]; const float* bv = (const float*)d_in[ix++];
  const float* Wo = (const float*)d_in[ix++]; const float* bo = (const float*)d_in[ix++];
  const float* gm = (const float*)d_in[ix++]; const float* bt = (const float*)d_in[ix++];

  char* ws = (char*)d_ws;
  dim3 blk(256);

  // ws layout (64 MB): WT4 8 | qp 4 | kp 16 | vt 16 | at 4 (alias qb) | kvb 16
  unsigned short* WT4 = (unsigned short*)(ws);
  unsigned short* qp  = (unsigned short*)(ws + (8ull  << 20));
  unsigned short* kp  = (unsigned short*)(ws + (12ull << 20));
  unsigned short* vt  = (unsigned short*)(ws + (28ull << 20));
  unsigned short* at  = (unsigned short*)(ws + (44ull << 20));
  unsigned short* qb  = at;                       // dead before attn
  unsigned short* kvb = (unsigned short*)(ws + (48ull << 20));

  cvt_kernel<<<dim3(1024), blk, 0, stream>>>(Q, qb, 262144);
  cvt_kernel<<<dim3(4096), blk, 0, stream>>>(K, kvb, 1048576);
  transpose4_kernel<<<dim3(16, 16, 4), blk, 0, stream>>>(Wq, Wk, Wv, Wo, WT4);

  gemm_bt64_kernel<<<dim3(32, 8), blk, 0, stream>>>(qb, WT4, bq, qp, 2048, 1024, 1024, 0.125f);
  gemm_bt_kernel<<<dim3(64, 8), blk, 0, stream>>>(kvb, WT4 + 1048576, bk, kp, 8192, 1024, 1024, 1.0f);
  cvt_kernel<<<dim3(4096), blk, 0, stream>>>(V, kvb, 1048576);
  gemm_vt_kernel<<<dim3(64, 8), blk, 0, stream>>>(kvb, WT4 + 2097152, bv, vt);

  attn_kernel<<<dim3(1024), blk, 0, stream>>>(qp, kp, vt, mask, at);

  gemm_bt64_kernel<<<dim3(32, 8), blk, 0, stream>>>(at, WT4 + 3145728, bo, qp, 2048, 1024, 1024, 1.0f);
  ln_kernel<<<dim3(2048), blk, 0, stream>>>(qp, Q, gm, bt, (float*)d_out);
}